// Round 17
// baseline (26.101 us; speedup 1.0000x reference)
//
#include <hip/hip_runtime.h>

#define NPART 128
#define NDIM  128
#define BATCH 4096
#define RQN   4                       // disjoint row-quarters per particle
#define NBLK  (NPART * RQN)           // 512 blocks
#define NXCD  8

typedef __attribute__((address_space(1))) const unsigned int guint;
typedef __attribute__((address_space(3))) unsigned int luint;

// ---------------------------------------------------------------------------
// Single fused kernel: 512 blocks x 256 threads.
// Block = (particle p, row-quarter rq): stages ONLY sigma rows
// [rq*32, rq*32+32) (16 KB, disjoint across blocks -> 8 MB total = unique,
// ZERO stage duplication vs R16's 32 MB), and computes those 32 output rows
// for the ENTIRE bucket of p (8-way sample split, ~4 samples/thread — same
// per-thread work as R16). Selection is the R16 full-scan rank (all 4
// rq-siblings agree); wout/indout written in rank loop by rq==0 blocks.
// ---------------------------------------------------------------------------
__global__ __launch_bounds__(256)
void mix_kernel(const float* __restrict__ gaussian,  // [BATCH, NDIM]
                const float* __restrict__ logp,      // [NPART]
                const float* __restrict__ pos,       // [NPART, NDIM]
                const float* __restrict__ sigma,     // [NPART, NDIM, NDIM]
                const int*   __restrict__ randind,   // [BATCH]
                float* __restrict__ out,             // [BATCH, NDIM]
                float* __restrict__ wout,            // [BATCH]
                float* __restrict__ indout) {        // [BATCH]
    const int g  = blockIdx.x;
    // XCD-chunked bijective swizzle (512 % 8 == 0): a particle's 4 siblings
    // land on one XCD -> shared y rows L2-hot after first use.
    const int sg = (g % NXCD) * (NBLK / NXCD) + g / NXCD;
    const int p  = sg >> 2;            // particle
    const int rq = sg & 3;             // row quarter: rows [rq*32, rq*32+32)
    const int t  = threadIdx.x;
    const int il = t & 31;             // local row 0..31
    const int oc = t >> 5;             // 0..7: sample split
    const int lane = t & 63, wid = t >> 6;

    __shared__ float4 smat[32 * 32];   // 16 KB: 32 rows x 32 col4, swizzled
    __shared__ int    wtot[4];
    __shared__ int    slist[144];      // full bucket (n ~ Poisson(32))
    __shared__ float  smx[2];          // softmax m, S

    // ---- 1. issue sigma row-quarter -> LDS async FIRST (needs only p) ----
    // LDS slot (r*32+c) holds sigma row (rq*32+r), col4 c^r (involution).
    {
        const float4* src = reinterpret_cast<const float4*>(sigma)
                            + (size_t)p * 4096 + rq * 1024;
        #pragma unroll
        for (int w = 0; w < 4; ++w) {
            const int idx = w * 256 + t;           // linear float4 LDS slot
            const int r = idx >> 5, c = idx & 31;
            const float4* gp = src + (r * 32 + (c ^ r));
            luint* lp = (luint*)(smat + (w * 256 + wid * 64)); // wave-uniform
            __builtin_amdgcn_global_load_lds((guint*)gp, lp, 16, 0, 0);
        }
    }

    // ---- 2. selection loads: thread t owns samples [16t, 16t+16) ----
    const int4* rnd4 = reinterpret_cast<const int4*>(randind);
    int mk[16];
    {
        int4 a = rnd4[t * 4 + 0], b = rnd4[t * 4 + 1],
             c = rnd4[t * 4 + 2], d = rnd4[t * 4 + 3];
        mk[0]=a.x;  mk[1]=a.y;  mk[2]=a.z;  mk[3]=a.w;
        mk[4]=b.x;  mk[5]=b.y;  mk[6]=b.z;  mk[7]=b.w;
        mk[8]=c.x;  mk[9]=c.y;  mk[10]=c.z; mk[11]=c.w;
        mk[12]=d.x; mk[13]=d.y; mk[14]=d.z; mk[15]=d.w;
    }

    // ---- 3. softmax scalars by wave 0 ----
    if (t < 64) {
        float a = logp[t], b = logp[t + 64];
        float m = fmaxf(a, b);
        #pragma unroll
        for (int o = 32; o > 0; o >>= 1) m = fmaxf(m, __shfl_xor(m, o));
        float ea = expf(a - m), eb = expf(b - m);
        float s = ea + eb;
        #pragma unroll
        for (int o = 32; o > 0; o >>= 1) s += __shfl_xor(s, o);
        if (t == 0) { smx[0] = m; smx[1] = s; }
    }

    // ---- 4. wave-shfl scan ----
    int cnt = 0;
    #pragma unroll
    for (int k = 0; k < 16; ++k) cnt += (mk[k] == p) ? 1 : 0;
    int v = cnt;                                   // inclusive wave scan
    #pragma unroll
    for (int o = 1; o < 64; o <<= 1) {
        int u = __shfl_up(v, o);
        if (lane >= o) v += u;
    }
    if (lane == 63) wtot[wid] = v;
    __syncthreads();                               // barrier #1
    int woff = 0;
    #pragma unroll
    for (int w = 0; w < 4; ++w) woff += (w < wid) ? wtot[w] : 0;
    const int base = woff + v - cnt;               // block-wide exclusive
    const int n    = wtot[0] + wtot[1] + wtot[2] + wtot[3];

    // ---- 5. rank loop: fill slist; rq==0 also emits wout/indout ----
    const float pw = expf(logp[p] - smx[0]) / smx[1];
    {
        int r = base;
        #pragma unroll
        for (int k = 0; k < 16; ++k) {
            if (mk[k] == p) {
                if (r < 144) slist[r] = t * 16 + k;
                if (rq == 0) {
                    wout[t * 16 + k]   = pw;
                    indout[t * 16 + k] = (float)p;   // exact for 0..127
                }
                ++r;
            }
        }
    }
    __syncthreads();                               // barrier #2 (drains glds)

    // ---- 6. row il -> 32 float4 regs ----
    float4 sr[32];
    #pragma unroll
    for (int u = 0; u < 32; ++u)
        sr[u] = smat[il * 32 + (u ^ il)];

    const float posv = pos[p * NDIM + rq * 32 + il];

    // ---- 7. per-sample: half-wave-uniform y loads + register fmacs ----
    for (int s = oc; s < n; s += 8) {
        const int sid = slist[s];                  // uniform per 32-lane half
        const float4* y = reinterpret_cast<const float4*>(
            gaussian + (size_t)sid * NDIM);
        float a0 = 0.f, a1 = 0.f, a2 = 0.f, a3 = 0.f;
        #pragma unroll
        for (int u = 0; u < 32; ++u) {
            float4 yv = y[u];                      // 2 lines per wave instr
            float4 sv = sr[u];
            a0 += sv.x * yv.x;  a1 += sv.y * yv.y;
            a2 += sv.z * yv.z;  a3 += sv.w * yv.w;
        }
        out[sid * NDIM + rq * 32 + il] = posv + ((a0 + a1) + (a2 + a3));
    }
}

extern "C" void kernel_launch(void* const* d_in, const int* in_sizes, int n_in,
                              void* d_out, int out_size, void* d_ws, size_t ws_size,
                              hipStream_t stream) {
    const float* gaussian = (const float*)d_in[0];   // [4096,128]
    const float* logp     = (const float*)d_in[1];   // [128,1]
    const float* pos      = (const float*)d_in[2];   // [128,128]
    const float* sigma    = (const float*)d_in[3];   // [128,128,128]
    const int*   randind  = (const int*)d_in[4];     // [4096]

    float* out    = (float*)d_out;            // [4096*128]
    float* wout   = out + BATCH * NDIM;       // [4096]
    float* indout = wout + BATCH;             // [4096]

    mix_kernel<<<NBLK, 256, 0, stream>>>(gaussian, logp, pos, sigma, randind,
                                         out, wout, indout);
}

// Round 18
// 22.139 us; speedup vs baseline: 1.1790x; 1.1790x over previous
//
#include <hip/hip_runtime.h>

#define NPART 128
#define NDIM  128
#define BATCH 4096
#define BPP   4                       // bucket quarters per particle
#define NBLK  (NPART * BPP)           // 512 blocks
#define NXCD  8

// ---------------------------------------------------------------------------
// Single fused kernel: 512 blocks x 256 threads. Block = (particle p, qtr q).
// R17 post-mortem: VGPR 244 -> 8% occupancy was the bottleneck. This version
// splits each sigma row across lane pairs (l, l^32) of one wave:
//   lane l: row = wid*32 + (l&31), colhalf = l>>5
//   sr[16] (64 VGPR) + y[16] in flight (64 VGPR) ~= 150 total, LDS ~1 KB.
// Sigma loads are direct global->reg (same 1024 L2 lines/block as glds path,
// no smat, no drain barrier, no ds_reads). Per sample: 16 broadcast y loads
// (2 addrs/wave), 64 fmacs, one shfl_xor(32) combine, lanes<32 store.
// Selection (softmax, wave-scan, rank -> quarter slist) identical to R16.
// ---------------------------------------------------------------------------
__global__ __launch_bounds__(256)
void mix_kernel(const float* __restrict__ gaussian,  // [BATCH, NDIM]
                const float* __restrict__ logp,      // [NPART]
                const float* __restrict__ pos,       // [NPART, NDIM]
                const float* __restrict__ sigma,     // [NPART, NDIM, NDIM]
                const int*   __restrict__ randind,   // [BATCH]
                float* __restrict__ out,             // [BATCH, NDIM]
                float* __restrict__ wout,            // [BATCH]
                float* __restrict__ indout) {        // [BATCH]
    const int g  = blockIdx.x;
    // XCD-chunked bijective swizzle (512 % 8 == 0): a particle's 4 sibling
    // blocks land on the same XCD -> sigma_p / y rows L2-shared.
    const int sg = (g % NXCD) * (NBLK / NXCD) + g / NXCD;
    const int p  = sg >> 2;            // particle
    const int q  = sg & 3;             // quarter of bucket
    const int t  = threadIdx.x;
    const int lane = t & 63, wid = t >> 6;
    const int row  = wid * 32 + (lane & 31);   // output row owned by lane pair
    const int half = lane >> 5;                // column half 0/1

    __shared__ int   wtot[4];
    __shared__ int   slist[160];               // sids of my quarter
    __shared__ float smx[2];                   // softmax m, S

    // ---- 1. selection loads first: thread t owns samples [16t, 16t+16) ----
    const int4* rnd4 = reinterpret_cast<const int4*>(randind);
    int mk[16];
    {
        int4 a = rnd4[t * 4 + 0], b = rnd4[t * 4 + 1],
             c = rnd4[t * 4 + 2], d = rnd4[t * 4 + 3];
        mk[0]=a.x;  mk[1]=a.y;  mk[2]=a.z;  mk[3]=a.w;
        mk[4]=b.x;  mk[5]=b.y;  mk[6]=b.z;  mk[7]=b.w;
        mk[8]=c.x;  mk[9]=c.y;  mk[10]=c.z; mk[11]=c.w;
        mk[12]=d.x; mk[13]=d.y; mk[14]=d.z; mk[15]=d.w;
    }

    // ---- 2. softmax scalars by wave 0 ----
    if (t < 64) {
        float a = logp[t], b = logp[t + 64];
        float m = fmaxf(a, b);
        #pragma unroll
        for (int o = 32; o > 0; o >>= 1) m = fmaxf(m, __shfl_xor(m, o));
        float ea = expf(a - m), eb = expf(b - m);
        float s = ea + eb;
        #pragma unroll
        for (int o = 32; o > 0; o >>= 1) s += __shfl_xor(s, o);
        if (t == 0) { smx[0] = m; smx[1] = s; }
    }

    // ---- 3. wave-shfl scan selection ----
    int cnt = 0;
    #pragma unroll
    for (int k = 0; k < 16; ++k) cnt += (mk[k] == p) ? 1 : 0;
    int v = cnt;                                   // inclusive wave scan
    #pragma unroll
    for (int o = 1; o < 64; o <<= 1) {
        int u = __shfl_up(v, o);
        if (lane >= o) v += u;
    }
    if (lane == 63) wtot[wid] = v;
    __syncthreads();                               // barrier #1
    int woff = 0;
    #pragma unroll
    for (int w = 0; w < 4; ++w) woff += (w < wid) ? wtot[w] : 0;
    const int base = woff + v - cnt;               // block-wide exclusive
    const int n    = wtot[0] + wtot[1] + wtot[2] + wtot[3];
    const int lo   = (n * q) / BPP;
    const int hi   = (n * (q + 1)) / BPP;
    const int nq   = hi - lo;
    if (nq == 0) return;               // uniform across block, safe

    // ---- 4a. sigma half-row -> 16 float4 registers (direct, L2-served) ----
    const float4* srow = reinterpret_cast<const float4*>(
        sigma + (size_t)p * NDIM * NDIM + row * NDIM + half * 64);
    float4 sr[16];
    #pragma unroll
    for (int u = 0; u < 16; ++u) sr[u] = srow[u];

    // ---- 4b. rank loop (runs under sigma loads) ----
    const float pw = expf(logp[p] - smx[0]) / smx[1];
    {
        int r = base;
        #pragma unroll
        for (int k = 0; k < 16; ++k) {
            if (mk[k] == p) {
                if (r >= lo && r < hi && (r - lo) < 160) slist[r - lo] = t * 16 + k;
                ++r;
            }
        }
    }
    const float posv = pos[p * NDIM + row];
    __syncthreads();                               // barrier #2 (slist ready)

    // ---- 5. per-sample: broadcast y half-row + fmacs + shfl combine ----
    for (int s = 0; s < nq; ++s) {
        const int sid = slist[s];                  // LDS broadcast, same addr
        const float4* y = reinterpret_cast<const float4*>(
            gaussian + (size_t)sid * NDIM + half * 64);
        float a0 = 0.f, a1 = 0.f, a2 = 0.f, a3 = 0.f;
        #pragma unroll
        for (int u = 0; u < 16; ++u) {
            float4 yv = y[u];                      // 2 addrs per wave
            float4 sv = sr[u];
            a0 += sv.x * yv.x;  a1 += sv.y * yv.y;
            a2 += sv.z * yv.z;  a3 += sv.w * yv.w;
        }
        float part = (a0 + a1) + (a2 + a3);
        float tot  = part + __shfl_xor(part, 32);  // combine halves
        if (half == 0)
            out[sid * NDIM + row] = posv + tot;
        if (t == 0) {
            wout[sid]   = pw;
            indout[sid] = (float)p;                // exact for 0..127
        }
    }
}

extern "C" void kernel_launch(void* const* d_in, const int* in_sizes, int n_in,
                              void* d_out, int out_size, void* d_ws, size_t ws_size,
                              hipStream_t stream) {
    const float* gaussian = (const float*)d_in[0];   // [4096,128]
    const float* logp     = (const float*)d_in[1];   // [128,1]
    const float* pos      = (const float*)d_in[2];   // [128,128]
    const float* sigma    = (const float*)d_in[3];   // [128,128,128]
    const int*   randind  = (const int*)d_in[4];     // [4096]

    float* out    = (float*)d_out;            // [4096*128]
    float* wout   = out + BATCH * NDIM;       // [4096]
    float* indout = wout + BATCH;             // [4096]

    mix_kernel<<<NBLK, 256, 0, stream>>>(gaussian, logp, pos, sigma, randind,
                                         out, wout, indout);
}

// Round 19
// 15.119 us; speedup vs baseline: 1.7264x; 1.4644x over previous
//
#include <hip/hip_runtime.h>

#define NPART 128
#define NDIM  128
#define BATCH 4096
#define BPP   4                       // blocks per particle
#define NBLK  (NPART * BPP)           // 512 blocks
#define NXCD  8

typedef __attribute__((address_space(1))) const unsigned int guint;
typedef __attribute__((address_space(3))) unsigned int luint;

#define DOT8(accA,accB,accC,accD,SRB,Y0,Y1,Y2,Y3,Y4,Y5,Y6,Y7)                 \
    accA += sr[SRB+0].x*Y0.x; accB += sr[SRB+0].y*Y0.y;                       \
    accC += sr[SRB+0].z*Y0.z; accD += sr[SRB+0].w*Y0.w;                       \
    accA += sr[SRB+1].x*Y1.x; accB += sr[SRB+1].y*Y1.y;                       \
    accC += sr[SRB+1].z*Y1.z; accD += sr[SRB+1].w*Y1.w;                       \
    accA += sr[SRB+2].x*Y2.x; accB += sr[SRB+2].y*Y2.y;                       \
    accC += sr[SRB+2].z*Y2.z; accD += sr[SRB+2].w*Y2.w;                       \
    accA += sr[SRB+3].x*Y3.x; accB += sr[SRB+3].y*Y3.y;                       \
    accC += sr[SRB+3].z*Y3.z; accD += sr[SRB+3].w*Y3.w;                       \
    accA += sr[SRB+4].x*Y4.x; accB += sr[SRB+4].y*Y4.y;                       \
    accC += sr[SRB+4].z*Y4.z; accD += sr[SRB+4].w*Y4.w;                       \
    accA += sr[SRB+5].x*Y5.x; accB += sr[SRB+5].y*Y5.y;                       \
    accC += sr[SRB+5].z*Y5.z; accD += sr[SRB+5].w*Y5.w;                       \
    accA += sr[SRB+6].x*Y6.x; accB += sr[SRB+6].y*Y6.y;                       \
    accC += sr[SRB+6].z*Y6.z; accD += sr[SRB+6].w*Y6.w;                       \
    accA += sr[SRB+7].x*Y7.x; accB += sr[SRB+7].y*Y7.y;                       \
    accC += sr[SRB+7].z*Y7.z; accD += sr[SRB+7].w*Y7.w;

// ---------------------------------------------------------------------------
// R16 structure (best: 15.5us) with ONE change: phase-5 y loads are software-
// pipelined with a quarter-row (8 x float4) A/B double buffer in NAMED
// registers (static indexing). Each 8-load burst issues before the previous
// quarter's 32 FMAs; the last quarter prefetches the next sample's first.
// VGPR ~210 < 256 -> occupancy unchanged (2 blocks/CU, LDS-capped).
// ---------------------------------------------------------------------------
__global__ __launch_bounds__(256)
void mix_kernel(const float* __restrict__ gaussian,  // [BATCH, NDIM]
                const float* __restrict__ logp,      // [NPART]
                const float* __restrict__ pos,       // [NPART, NDIM]
                const float* __restrict__ sigma,     // [NPART, NDIM, NDIM]
                const int*   __restrict__ randind,   // [BATCH]
                float* __restrict__ out,             // [BATCH, NDIM]
                float* __restrict__ wout,            // [BATCH]
                float* __restrict__ indout) {        // [BATCH]
    const int g  = blockIdx.x;
    const int sg = (g % NXCD) * (NBLK / NXCD) + g / NXCD;
    const int p  = sg >> 2;            // particle
    const int q  = sg & 3;             // quarter of bucket
    const int t  = threadIdx.x;
    const int i  = t & 127;            // output row
    const int hf = t >> 7;             // sample-parity half
    const int lane = t & 63, wid = t >> 6;

    __shared__ float4 smat[NDIM * 32];           // 64 KB swizzled sigma_p
    __shared__ int    wtot[4];
    __shared__ int    slist[160];                // sids of my quarter
    __shared__ float  smx[2];                    // softmax m, S

    // ---- 1. selection loads first: thread t owns samples [16t, 16t+16) ----
    const int4* rnd4 = reinterpret_cast<const int4*>(randind);
    int mk[16];
    {
        int4 a = rnd4[t * 4 + 0], b = rnd4[t * 4 + 1],
             c = rnd4[t * 4 + 2], d = rnd4[t * 4 + 3];
        mk[0]=a.x;  mk[1]=a.y;  mk[2]=a.z;  mk[3]=a.w;
        mk[4]=b.x;  mk[5]=b.y;  mk[6]=b.z;  mk[7]=b.w;
        mk[8]=c.x;  mk[9]=c.y;  mk[10]=c.z; mk[11]=c.w;
        mk[12]=d.x; mk[13]=d.y; mk[14]=d.z; mk[15]=d.w;
    }

    // ---- 2. softmax scalars by wave 0 ----
    if (t < 64) {
        float a = logp[t], b = logp[t + 64];
        float m = fmaxf(a, b);
        #pragma unroll
        for (int o = 32; o > 0; o >>= 1) m = fmaxf(m, __shfl_xor(m, o));
        float ea = expf(a - m), eb = expf(b - m);
        float s = ea + eb;
        #pragma unroll
        for (int o = 32; o > 0; o >>= 1) s += __shfl_xor(s, o);
        if (t == 0) { smx[0] = m; smx[1] = s; }
    }

    // ---- 3. wave-shfl scan selection ----
    int cnt = 0;
    #pragma unroll
    for (int k = 0; k < 16; ++k) cnt += (mk[k] == p) ? 1 : 0;
    int v = cnt;                                   // inclusive wave scan
    #pragma unroll
    for (int o = 1; o < 64; o <<= 1) {
        int u = __shfl_up(v, o);
        if (lane >= o) v += u;
    }
    if (lane == 63) wtot[wid] = v;
    __syncthreads();                               // barrier #1
    int woff = 0;
    #pragma unroll
    for (int w = 0; w < 4; ++w) woff += (w < wid) ? wtot[w] : 0;
    const int base = woff + v - cnt;               // block-wide exclusive
    const int n    = wtot[0] + wtot[1] + wtot[2] + wtot[3];
    const int lo   = (n * q) / BPP;
    const int hi   = (n * (q + 1)) / BPP;
    const int nq   = hi - lo;
    if (nq == 0) return;               // uniform across block, safe

    // ---- 4a. issue sigma -> LDS async, pre-swizzled source (G21/m173) ----
    {
        const float4* src = reinterpret_cast<const float4*>(sigma)
                            + (size_t)p * 4096;
        #pragma unroll
        for (int w = 0; w < 16; ++w) {
            const int idx = w * 256 + t;           // linear float4 LDS slot
            const int r = idx >> 5, c = idx & 31;
            const float4* gp = src + (r * 32 + (c ^ (r & 31)));
            luint* lp = (luint*)(smat + (w * 256 + wid * 64)); // wave-uniform
            __builtin_amdgcn_global_load_lds((guint*)gp, lp, 16, 0, 0);
        }
    }

    // ---- 4b. rank loop (runs while sigma streams) ----
    const float pw = expf(logp[p] - smx[0]) / smx[1];
    {
        int r = base;
        #pragma unroll
        for (int k = 0; k < 16; ++k) {
            if (mk[k] == p) {
                if (r >= lo && r < hi) slist[r - lo] = t * 16 + k;
                ++r;
            }
        }
    }
    __syncthreads();                               // barrier #2 (drains glds)

    // ---- 5. row i -> 32 float4 regs; pipelined sample loop ----
    float4 sr[32];
    #pragma unroll
    for (int u = 0; u < 32; ++u)
        sr[u] = smat[i * 32 + (u ^ (i & 31))];

    const float posv = pos[p * NDIM + i];

    int s = hf;
    if (s < nq) {
        const float4* y = reinterpret_cast<const float4*>(
            gaussian + (size_t)__builtin_amdgcn_readfirstlane(slist[s]) * NDIM);
        float4 A0=y[0],A1=y[1],A2=y[2],A3=y[3],A4=y[4],A5=y[5],A6=y[6],A7=y[7];
        float4 B0,B1,B2,B3,B4,B5,B6,B7;
        for (; s < nq; s += 2) {
            const int sid = __builtin_amdgcn_readfirstlane(slist[s]);
            y = reinterpret_cast<const float4*>(gaussian + (size_t)sid * NDIM);
            const int sn = (s + 2 < nq) ? __builtin_amdgcn_readfirstlane(slist[s + 2]) : sid;
            const float4* yn = reinterpret_cast<const float4*>(
                gaussian + (size_t)sn * NDIM);
            float a0 = 0.f, a1 = 0.f, a2 = 0.f, a3 = 0.f;
            // q0 in A; prefetch q1 -> B; compute q0
            B0=y[8];B1=y[9];B2=y[10];B3=y[11];B4=y[12];B5=y[13];B6=y[14];B7=y[15];
            DOT8(a0,a1,a2,a3, 0, A0,A1,A2,A3,A4,A5,A6,A7)
            // q1 in B; prefetch q2 -> A; compute q1
            A0=y[16];A1=y[17];A2=y[18];A3=y[19];A4=y[20];A5=y[21];A6=y[22];A7=y[23];
            DOT8(a0,a1,a2,a3, 8, B0,B1,B2,B3,B4,B5,B6,B7)
            // q2 in A; prefetch q3 -> B; compute q2
            B0=y[24];B1=y[25];B2=y[26];B3=y[27];B4=y[28];B5=y[29];B6=y[30];B7=y[31];
            DOT8(a0,a1,a2,a3, 16, A0,A1,A2,A3,A4,A5,A6,A7)
            // q3 in B; prefetch next sample's q0 -> A; compute q3
            A0=yn[0];A1=yn[1];A2=yn[2];A3=yn[3];A4=yn[4];A5=yn[5];A6=yn[6];A7=yn[7];
            DOT8(a0,a1,a2,a3, 24, B0,B1,B2,B3,B4,B5,B6,B7)
            out[sid * NDIM + i] = posv + ((a0 + a1) + (a2 + a3));
            if (i == 0) {
                wout[sid]   = pw;
                indout[sid] = (float)p;            // exact for 0..127
            }
        }
    }
}

extern "C" void kernel_launch(void* const* d_in, const int* in_sizes, int n_in,
                              void* d_out, int out_size, void* d_ws, size_t ws_size,
                              hipStream_t stream) {
    const float* gaussian = (const float*)d_in[0];   // [4096,128]
    const float* logp     = (const float*)d_in[1];   // [128,1]
    const float* pos      = (const float*)d_in[2];   // [128,128]
    const float* sigma    = (const float*)d_in[3];   // [128,128,128]
    const int*   randind  = (const int*)d_in[4];     // [4096]

    float* out    = (float*)d_out;            // [4096*128]
    float* wout   = out + BATCH * NDIM;       // [4096]
    float* indout = wout + BATCH;             // [4096]

    mix_kernel<<<NBLK, 256, 0, stream>>>(gaussian, logp, pos, sigma, randind,
                                         out, wout, indout);
}